// Round 3
// baseline (1562.136 us; speedup 1.0000x reference)
//
#include <hip/hip_runtime.h>
#include <math.h>
#include <stdint.h>

#define N_NODES 100000
#define N_EDGES 1600000
#define IN_DIM  256
#define HID     128
#define EPS_C   0.3f

// bucket partition for write-local processing
#define NPB      128              // nodes per bucket (dst >> 7)
#define NBKT     782              // ceil(N_NODES / NPB)
#define NBKT_P   784              // padded (2 slots per scan thread, 392 used)
#define BCAP     3072             // per-bucket edge capacity (mean 2048, +22 sigma)
#define S1_CHUNK 8192             // edges per partition block
#define S1_BLOCKS 196             // ceil(N_EDGES / S1_CHUNK)

// packed edge word: bits [16:0] = src (100000 < 2^17), bits [23:17] = dst & 127
#define PK_SRC(p)  ((p) & 0x1FFFF)
#define PK_LI(p)   ((p) >> 17)

typedef __attribute__((ext_vector_type(8))) __bf16 bf16x8;
typedef __attribute__((ext_vector_type(4))) float  f32x4;
typedef __attribute__((ext_vector_type(8))) unsigned short ushort8;

static __device__ __forceinline__ unsigned short f2bf(float f) {
    unsigned u = __float_as_uint(f);
    unsigned r = (u + 0x7fffu + ((u >> 16) & 1u)) >> 16;
    return (unsigned short)r;
}
static __device__ __forceinline__ float bf2f(unsigned short s) {
    return __uint_as_float((unsigned)s << 16);
}
// branch-free tanh: 1 - 2/(exp2(2x*log2e)+1); correct limits at +-inf
static __device__ __forceinline__ float fast_tanh(float x) {
    float e = __builtin_exp2f(x * 2.8853900817779268f);  // 2*log2(e)
    return 1.0f - 2.0f / (e + 1.0f);
}

// ---------------------------------------------------------------------------
// w1 -> bf16 preconvert (one-time tiny kernel, 32768 elems)
// ---------------------------------------------------------------------------
__global__ __launch_bounds__(256) void convert_w1_kernel(const float* __restrict__ w1,
                                                         unsigned short* __restrict__ w1b) {
    int i = blockIdx.x * 256 + threadIdx.x;
    if (i * 4 >= HID * IN_DIM) return;
    float4 v = *(const float4*)&w1[i * 4];
    ushort4 r;
    r.x = f2bf(v.x); r.y = f2bf(v.y); r.z = f2bf(v.z); r.w = f2bf(v.w);
    *(ushort4*)&w1b[i * 4] = r;
}

// ---------------------------------------------------------------------------
// 1) Partition: bucket-group edges by dst>>7 via LDS counting sort.
//    Coalesced run-writes of PACKED 4B edge words into ebuf[b*BCAP ...].
// ---------------------------------------------------------------------------
__global__ __launch_bounds__(512) void partition_kernel(const int* __restrict__ src,
                                                        const int* __restrict__ dst,
                                                        int* __restrict__ gcur,
                                                        int* __restrict__ ebuf) {
    __shared__ int hist[NBKT_P];
    __shared__ int base[NBKT_P];
    __shared__ int gpos[NBKT_P];
    __shared__ int cur[NBKT_P];
    __shared__ int seg[512];
    __shared__ int2 staged[S1_CHUNK];

    int t = threadIdx.x;
    for (int i = t; i < NBKT_P; i += 512) hist[i] = 0;
    __syncthreads();

    int base4 = blockIdx.x * (S1_CHUNK / 4);     // int4 index into src/dst
    int rem4  = N_EDGES / 4 - base4;

    int4 sv[4], dv[4];
#pragma unroll
    for (int j = 0; j < 4; j++) {
        int i4 = j * 512 + t;
        if (i4 < rem4) {
            sv[j] = *(const int4*)&src[(base4 + i4) * 4];
            dv[j] = *(const int4*)&dst[(base4 + i4) * 4];
        } else {
            dv[j] = make_int4(-1, -1, -1, -1);   // sentinel: invalid
        }
    }
#pragma unroll
    for (int j = 0; j < 4; j++) {
        if (dv[j].x >= 0) {
            atomicAdd(&hist[dv[j].x >> 7], 1);
            atomicAdd(&hist[dv[j].y >> 7], 1);
            atomicAdd(&hist[dv[j].z >> 7], 1);
            atomicAdd(&hist[dv[j].w >> 7], 1);
        }
    }
    __syncthreads();

    // block-exclusive scan over NBKT_P buckets: 2 slots per thread (t < 392)
    int h0 = 0, h1 = 0;
    if (t < NBKT_P / 2) { h0 = hist[2 * t]; h1 = hist[2 * t + 1]; }
    seg[t] = h0 + h1;
    __syncthreads();
    for (int off = 1; off < 512; off <<= 1) {
        int a = (t >= off) ? seg[t - off] : 0;
        __syncthreads();
        seg[t] += a;
        __syncthreads();
    }
    if (t < NBKT_P / 2) {
        int excl = seg[t] - (h0 + h1);
        base[2 * t]     = excl;
        cur[2 * t]      = excl;
        base[2 * t + 1] = excl + h0;
        cur[2 * t + 1]  = excl + h0;
        if (h0 > 0) gpos[2 * t]     = atomicAdd(&gcur[2 * t], h0);
        if (h1 > 0) gpos[2 * t + 1] = atomicAdd(&gcur[2 * t + 1], h1);
    }
    __syncthreads();

    // scatter register-held edges into bucket-sorted LDS staging
#pragma unroll
    for (int j = 0; j < 4; j++) {
        if (dv[j].x >= 0) {
            int p;
            p = atomicAdd(&cur[dv[j].x >> 7], 1); staged[p] = make_int2(sv[j].x, dv[j].x);
            p = atomicAdd(&cur[dv[j].y >> 7], 1); staged[p] = make_int2(sv[j].y, dv[j].y);
            p = atomicAdd(&cur[dv[j].z >> 7], 1); staged[p] = make_int2(sv[j].z, dv[j].z);
            p = atomicAdd(&cur[dv[j].w >> 7], 1); staged[p] = make_int2(sv[j].w, dv[j].w);
        }
    }
    __syncthreads();

    // copy out: consecutive i within a bucket -> consecutive global slots
    int n = N_EDGES - base4 * 4;
    if (n > S1_CHUNK) n = S1_CHUNK;
    for (int i = t; i < n; i += 512) {
        int2 e = staged[i];
        int b = e.y >> 7;
        int off2 = gpos[b] + (i - base[b]);
        if (off2 < BCAP) ebuf[(size_t)b * BCAP + off2] = ((e.y & (NPB - 1)) << 17) | e.x;
    }
}

// ---------------------------------------------------------------------------
// 2) Per-bucket degree histogram -> nrm only (no CSR scan needed anymore).
// ---------------------------------------------------------------------------
__global__ __launch_bounds__(512) void deg_kernel(const int* __restrict__ gcur,
                                                  const int* __restrict__ ebuf,
                                                  float* __restrict__ nrm) {
    __shared__ int dcnt[NPB];
    int b = blockIdx.x;
    int t = threadIdx.x;
    if (t < NPB) dcnt[t] = 0;
    __syncthreads();

    int ecnt = gcur[b];
    if (ecnt > BCAP) ecnt = BCAP;
    for (int j = t; j < ecnt; j += 512)
        atomicAdd(&dcnt[PK_LI(ebuf[(size_t)b * BCAP + j])], 1);
    __syncthreads();

    int nbase = b * NPB;
    int nn = N_NODES - nbase;
    if (nn > NPB) nn = NPB;
    if (t < nn) nrm[nbase + t] = rsqrtf(fmaxf((float)dcnt[t], 1.0f));
}

// ---------------------------------------------------------------------------
// 3) MFMA GEMM: h = relu(x @ w1^T + b1), bf16, fused gate dots.
//    Block = 256 thr (4 waves), tile M=64 N=128, BK=32, 16x16x32 MFMA.
// ---------------------------------------------------------------------------
__global__ __launch_bounds__(256) void gemm_kernel(const float* __restrict__ x,
                                                   const unsigned short* __restrict__ w1b,
                                                   const float* __restrict__ b1,
                                                   const float* __restrict__ gw,
                                                   const float* __restrict__ nrm,
                                                   unsigned short* __restrict__ h,
                                                   float2* __restrict__ pd_pack,
                                                   float2* __restrict__ ps_pack) {
    __shared__ unsigned short As[64 * 40];   // [m][k] bf16, stride 40
    __shared__ unsigned short Bs[128 * 40];  // [n][k] bf16, stride 40

    int tid = threadIdx.x;
    int bm = blockIdx.x * 64;

    int wv   = tid >> 6;
    int lane = tid & 63;
    int col  = lane & 15;
    int kq   = lane >> 4;

    f32x4 acc[8];
#pragma unroll
    for (int nf = 0; nf < 8; nf++) acc[nf] = (f32x4){0.f, 0.f, 0.f, 0.f};

    int am = tid >> 2;            // 0..63
    int ak = (tid & 3) * 8;       // 0,8,16,24
    int bn = tid >> 1;            // 0..127
    int bk = (tid & 1) * 16;      // 0,16
    int agm = bm + am;

    for (int k0 = 0; k0 < IN_DIM; k0 += 32) {
        // stage A: 64x32 f32 -> bf16 (8 floats/thread)
        float4 a0 = {0,0,0,0}, a1 = {0,0,0,0};
        if (agm < N_NODES) {
            const float* p = &x[agm * IN_DIM + k0 + ak];
            a0 = *(const float4*)p;
            a1 = *(const float4*)(p + 4);
        }
        ushort8 av;
        av[0]=f2bf(a0.x); av[1]=f2bf(a0.y); av[2]=f2bf(a0.z); av[3]=f2bf(a0.w);
        av[4]=f2bf(a1.x); av[5]=f2bf(a1.y); av[6]=f2bf(a1.z); av[7]=f2bf(a1.w);
        // stage B: already bf16 (16 elems = 2 x ushort8 per thread, no convert)
        ushort8 bv0 = *(const ushort8*)&w1b[bn * IN_DIM + k0 + bk];
        ushort8 bv1 = *(const ushort8*)&w1b[bn * IN_DIM + k0 + bk + 8];

        __syncthreads();
        *(ushort8*)&As[am * 40 + ak] = av;
        *(ushort8*)&Bs[bn * 40 + bk] = bv0;
        *(ushort8*)&Bs[bn * 40 + bk + 8] = bv1;
        __syncthreads();

        bf16x8 afrag = *(bf16x8*)&As[(wv * 16 + col) * 40 + kq * 8];
#pragma unroll
        for (int nf = 0; nf < 8; nf++) {
            bf16x8 bfrag = *(bf16x8*)&Bs[(nf * 16 + col) * 40 + kq * 8];
            acc[nf] = __builtin_amdgcn_mfma_f32_16x16x32_bf16(afrag, bfrag, acc[nf], 0, 0, 0);
        }
    }

    float bias[8], wd[8], wsv[8];
#pragma unroll
    for (int nf = 0; nf < 8; nf++) {
        bias[nf] = b1[nf * 16 + col];
        wd[nf]   = gw[nf * 16 + col];
        wsv[nf]  = gw[HID + nf * 16 + col];
    }
#pragma unroll
    for (int r = 0; r < 4; r++) {
        int gm = bm + wv * 16 + kq * 4 + r;   // uniform across the 16 col-lanes
        float pd = 0.f, ps = 0.f;
        bool ok = (gm < N_NODES);
#pragma unroll
        for (int nf = 0; nf < 8; nf++) {
            float v = fmaxf(acc[nf][r] + bias[nf], 0.f);
            pd = fmaf(v, wd[nf], pd);
            ps = fmaf(v, wsv[nf], ps);
            if (ok) h[gm * HID + nf * 16 + col] = f2bf(v);
        }
#pragma unroll
        for (int m = 1; m < 16; m <<= 1) {
            pd += __shfl_xor(pd, m);
            ps += __shfl_xor(ps, m);
        }
        if (ok && col == 0) {
            float nv = nrm[gm];
            pd_pack[gm] = make_float2(pd, nv);
            ps_pack[gm] = make_float2(ps, nv);
        }
    }
}

// ---------------------------------------------------------------------------
// 4) Fused scatter+aggregate: one block per dst-bucket. z-tile (128 nodes x
//    128 ch f32 = 64 KB) lives in LDS; per edge: gather h-row (one dword/lane
//    = 256B coalesced), compute gate coef inline, ds_add_f32 accumulate.
//    Epilogue: out = EPS*h + z, coalesced. Kills epack round-trip + CSR.
// ---------------------------------------------------------------------------
#define EDGE_BODY(P)                                                          \
    {                                                                         \
        int   s_  = PK_SRC(P);                                                \
        int   li_ = PK_LI(P);                                                 \
        unsigned hv_ = *(const unsigned*)&h[(size_t)s_ * HID + lane * 2];     \
        float2 psp_ = ps_pack[s_];                                            \
        float2 pdp_ = pdl[li_];                                               \
        float  c_ = fast_tanh(pdp_.x + psp_.x + gbv) * pdp_.y * psp_.y;       \
        atomicAdd(&z[li_ * HID + lane * 2],                                   \
                  c_ * bf2f((unsigned short)(hv_ & 0xffffu)));                \
        atomicAdd(&z[li_ * HID + lane * 2 + 1],                               \
                  c_ * bf2f((unsigned short)(hv_ >> 16)));                    \
    }

__global__ __launch_bounds__(512) void spagg_kernel(const int* __restrict__ gcur,
                                                    const int* __restrict__ ebuf,
                                                    const float2* __restrict__ pd_pack,
                                                    const float2* __restrict__ ps_pack,
                                                    const float* __restrict__ gb,
                                                    const unsigned short* __restrict__ h,
                                                    float* __restrict__ out) {
    __shared__ float  z[NPB * HID];    // 64 KB
    __shared__ float2 pdl[NPB];        // 1 KB
    __shared__ int    eloc[BCAP];      // 12 KB

    int b = blockIdx.x;
    int t = threadIdx.x;
    int nbase = b * NPB;

    f32x4* z4 = (f32x4*)z;
#pragma unroll
    for (int i = 0; i < (NPB * HID / 4) / 512; i++)
        z4[i * 512 + t] = (f32x4){0.f, 0.f, 0.f, 0.f};

    int nn = N_NODES - nbase;
    if (nn > NPB) nn = NPB;
    if (t < nn) pdl[t] = pd_pack[nbase + t];

    int ecnt = gcur[b];
    if (ecnt > BCAP) ecnt = BCAP;
    for (int i = t; i < ecnt; i += 512) eloc[i] = ebuf[(size_t)b * BCAP + i];
    __syncthreads();

    float gbv = gb[0];
    int lane = t & 63;
    int w    = t >> 6;    // wave id 0..7

    // main loop: each wave owns 4 consecutive edges per 32-edge stride
    int E32 = ecnt & ~31;
    for (int j0 = w * 4; j0 < E32; j0 += 32) {
        int p0 = eloc[j0], p1 = eloc[j0 + 1], p2 = eloc[j0 + 2], p3 = eloc[j0 + 3];
        EDGE_BODY(p0);
        EDGE_BODY(p1);
        EDGE_BODY(p2);
        EDGE_BODY(p3);
    }
    // tail (< 32 edges): one strided pass with guards
#pragma unroll
    for (int u = 0; u < 4; u++) {
        int j = E32 + w * 4 + u;
        if (j < ecnt) { int p = eloc[j]; EDGE_BODY(p); }
    }
    __syncthreads();

    // epilogue: out = EPS*h + z (coalesced float4)
#pragma unroll
    for (int i0 = 0; i0 < (NPB * HID / 4) / 512; i0++) {
        int i = i0 * 512 + t;
        int row = i >> 5;                    // 32 float4-groups per row
        int node = nbase + row;
        if (node < N_NODES) {
            int c0 = (i & 31) * 4;
            ushort4 hv = *(const ushort4*)&h[(size_t)node * HID + c0];
            f32x4 o;
            o.x = fmaf(EPS_C, bf2f(hv.x), z[row * HID + c0 + 0]);
            o.y = fmaf(EPS_C, bf2f(hv.y), z[row * HID + c0 + 1]);
            o.z = fmaf(EPS_C, bf2f(hv.z), z[row * HID + c0 + 2]);
            o.w = fmaf(EPS_C, bf2f(hv.w), z[row * HID + c0 + 3]);
            __builtin_nontemporal_store(o, (f32x4*)&out[(size_t)node * HID + c0]);
        }
    }
}

// ---------------------------------------------------------------------------
extern "C" void kernel_launch(void* const* d_in, const int* in_sizes, int n_in,
                              void* d_out, int out_size, void* d_ws, size_t ws_size,
                              hipStream_t stream) {
    const float* x  = (const float*)d_in[0];
    const int*   ei = (const int*)d_in[1];
    const float* w1 = (const float*)d_in[2];
    const float* b1 = (const float*)d_in[3];
    const float* gw = (const float*)d_in[4];
    const float* gb = (const float*)d_in[5];
    float* out = (float*)d_out;

    const int* src = ei;
    const int* dst = ei + N_EDGES;

    uintptr_t base = (uintptr_t)d_ws;
    size_t off = 0;
    auto alloc = [&](size_t bytes) -> void* {
        void* p = (void*)(base + off);
        off += (bytes + 255) & ~(size_t)255;
        return p;
    };
    unsigned short* h   = (unsigned short*)alloc((size_t)N_NODES * HID * 2);  // 25.6 MB
    float2* pd_pack     = (float2*)alloc((size_t)N_NODES * 8);
    float2* ps_pack     = (float2*)alloc((size_t)N_NODES * 8);
    float*  nrm         = (float*)alloc((size_t)N_NODES * 4);
    unsigned short* w1b = (unsigned short*)alloc((size_t)HID * IN_DIM * 2);
    int*    gcur        = (int*)alloc((size_t)NBKT * 4);
    int*    ebuf        = (int*)alloc((size_t)NBKT * BCAP * 4);               // 9.6 MB

    (void)hipMemsetAsync(gcur, 0, (size_t)NBKT * 4, stream);

    convert_w1_kernel<<<(HID * IN_DIM / 4 + 255) / 256, 256, 0, stream>>>(w1, w1b);
    partition_kernel<<<S1_BLOCKS, 512, 0, stream>>>(src, dst, gcur, ebuf);
    deg_kernel<<<NBKT, 512, 0, stream>>>(gcur, ebuf, nrm);
    gemm_kernel<<<(N_NODES + 63) / 64, 256, 0, stream>>>(x, w1b, b1, gw, nrm,
                                                         h, pd_pack, ps_pack);
    spagg_kernel<<<NBKT, 512, 0, stream>>>(gcur, ebuf, pd_pack, ps_pack, gb, h, out);
}

// Round 4
// 313.939 us; speedup vs baseline: 4.9759x; 4.9759x over previous
//
#include <hip/hip_runtime.h>
#include <math.h>
#include <stdint.h>

#define N_NODES 100000
#define N_EDGES 1600000
#define IN_DIM  256
#define HID     128
#define EPS_C   0.3f

// bucket partition for write-local CSR scatter
#define NPB      128              // nodes per bucket (dst >> 7)
#define NBKT     782              // ceil(N_NODES / NPB)
#define NBKT_P   784              // padded (2 slots per scan thread, 392 used)
#define BCAP     3072             // per-bucket edge capacity (mean 2048, +22 sigma)
#define S1_CHUNK 4096             // edges per partition block (391 blocks -> all CUs busy)
#define S1_BLOCKS 391             // ceil(N_EDGES / S1_CHUNK)

// packed edge word: bits [16:0] = src (100000 < 2^17), bits [23:17] = dst & 127
#define PK_SRC(p)  ((p) & 0x1FFFF)
#define PK_LI(p)   ((p) >> 17)

typedef __attribute__((ext_vector_type(8))) __bf16 bf16x8;
typedef __attribute__((ext_vector_type(4))) float  f32x4;
typedef __attribute__((ext_vector_type(8))) unsigned short ushort8;

static __device__ __forceinline__ unsigned short f2bf(float f) {
    unsigned u = __float_as_uint(f);
    unsigned r = (u + 0x7fffu + ((u >> 16) & 1u)) >> 16;
    return (unsigned short)r;
}
static __device__ __forceinline__ float bf2f(unsigned short s) {
    return __uint_as_float((unsigned)s << 16);
}
// branch-free tanh: 1 - 2/(exp2(2x*log2e)+1); correct limits at +-inf
static __device__ __forceinline__ float fast_tanh(float x) {
    float e = __builtin_exp2f(x * 2.8853900817779268f);  // 2*log2(e)
    return 1.0f - 2.0f / (e + 1.0f);
}

// ---------------------------------------------------------------------------
// w1 -> bf16 preconvert (one-time tiny kernel, 32768 elems)
// ---------------------------------------------------------------------------
__global__ __launch_bounds__(256) void convert_w1_kernel(const float* __restrict__ w1,
                                                         unsigned short* __restrict__ w1b) {
    int i = blockIdx.x * 256 + threadIdx.x;
    if (i * 4 >= HID * IN_DIM) return;
    float4 v = *(const float4*)&w1[i * 4];
    ushort4 r;
    r.x = f2bf(v.x); r.y = f2bf(v.y); r.z = f2bf(v.z); r.w = f2bf(v.w);
    *(ushort4*)&w1b[i * 4] = r;
}

// ---------------------------------------------------------------------------
// 1) Partition: bucket-group edges by dst>>7 via LDS counting sort.
//    Coalesced run-writes of PACKED 4B edge words into ebuf[b*BCAP ...].
//    S1_CHUNK=4096 -> 391 blocks, ~47KB LDS -> 3 blocks/CU.
// ---------------------------------------------------------------------------
__global__ __launch_bounds__(512) void partition_kernel(const int* __restrict__ src,
                                                        const int* __restrict__ dst,
                                                        int* __restrict__ gcur,
                                                        int* __restrict__ ebuf) {
    __shared__ int hist[NBKT_P];
    __shared__ int base[NBKT_P];
    __shared__ int gpos[NBKT_P];
    __shared__ int cur[NBKT_P];
    __shared__ int seg[512];
    __shared__ int2 staged[S1_CHUNK];

    int t = threadIdx.x;
    for (int i = t; i < NBKT_P; i += 512) hist[i] = 0;
    __syncthreads();

    int base4 = blockIdx.x * (S1_CHUNK / 4);     // int4 index into src/dst
    int rem4  = N_EDGES / 4 - base4;

    int4 sv[2], dv[2];
#pragma unroll
    for (int j = 0; j < 2; j++) {
        int i4 = j * 512 + t;
        if (i4 < rem4) {
            sv[j] = *(const int4*)&src[(base4 + i4) * 4];
            dv[j] = *(const int4*)&dst[(base4 + i4) * 4];
        } else {
            dv[j] = make_int4(-1, -1, -1, -1);   // sentinel: invalid
        }
    }
#pragma unroll
    for (int j = 0; j < 2; j++) {
        if (dv[j].x >= 0) {
            atomicAdd(&hist[dv[j].x >> 7], 1);
            atomicAdd(&hist[dv[j].y >> 7], 1);
            atomicAdd(&hist[dv[j].z >> 7], 1);
            atomicAdd(&hist[dv[j].w >> 7], 1);
        }
    }
    __syncthreads();

    // block-exclusive scan over NBKT_P buckets: 2 slots per thread (t < 392)
    int h0 = 0, h1 = 0;
    if (t < NBKT_P / 2) { h0 = hist[2 * t]; h1 = hist[2 * t + 1]; }
    seg[t] = h0 + h1;
    __syncthreads();
    for (int off = 1; off < 512; off <<= 1) {
        int a = (t >= off) ? seg[t - off] : 0;
        __syncthreads();
        seg[t] += a;
        __syncthreads();
    }
    if (t < NBKT_P / 2) {
        int excl = seg[t] - (h0 + h1);
        base[2 * t]     = excl;
        cur[2 * t]      = excl;
        base[2 * t + 1] = excl + h0;
        cur[2 * t + 1]  = excl + h0;
        if (h0 > 0) gpos[2 * t]     = atomicAdd(&gcur[2 * t], h0);
        if (h1 > 0) gpos[2 * t + 1] = atomicAdd(&gcur[2 * t + 1], h1);
    }
    __syncthreads();

    // scatter register-held edges into bucket-sorted LDS staging
#pragma unroll
    for (int j = 0; j < 2; j++) {
        if (dv[j].x >= 0) {
            int p;
            p = atomicAdd(&cur[dv[j].x >> 7], 1); staged[p] = make_int2(sv[j].x, dv[j].x);
            p = atomicAdd(&cur[dv[j].y >> 7], 1); staged[p] = make_int2(sv[j].y, dv[j].y);
            p = atomicAdd(&cur[dv[j].z >> 7], 1); staged[p] = make_int2(sv[j].z, dv[j].z);
            p = atomicAdd(&cur[dv[j].w >> 7], 1); staged[p] = make_int2(sv[j].w, dv[j].w);
        }
    }
    __syncthreads();

    // copy out: consecutive i within a bucket -> consecutive global slots
    int n = N_EDGES - base4 * 4;
    if (n > S1_CHUNK) n = S1_CHUNK;
    for (int i = t; i < n; i += 512) {
        int2 e = staged[i];
        int b = e.y >> 7;
        int off2 = gpos[b] + (i - base[b]);
        if (off2 < BCAP) ebuf[(size_t)b * BCAP + off2] = ((e.y & (NPB - 1)) << 17) | e.x;
    }
}

// ---------------------------------------------------------------------------
// 2) Exclusive scan of bucket totals gcur[NBKT] -> bstart (one block).
// ---------------------------------------------------------------------------
__global__ __launch_bounds__(512) void bscan_kernel(const int* __restrict__ gcur,
                                                    int* __restrict__ bstart) {
    __shared__ int s[512];
    int t = threadIdx.x;
    int a0 = 0, a1 = 0;
    if (t < NBKT_P / 2) {
        a0 = (2 * t     < NBKT) ? gcur[2 * t]     : 0;
        a1 = (2 * t + 1 < NBKT) ? gcur[2 * t + 1] : 0;
    }
    s[t] = a0 + a1;
    __syncthreads();
    for (int off = 1; off < 512; off <<= 1) {
        int a = (t >= off) ? s[t - off] : 0;
        __syncthreads();
        s[t] += a;
        __syncthreads();
    }
    if (t < NBKT_P / 2) {
        int excl = s[t] - (a0 + a1);
        if (2 * t     < NBKT) bstart[2 * t]     = excl;
        if (2 * t + 1 < NBKT) bstart[2 * t + 1] = excl + a0;
    }
}

// ---------------------------------------------------------------------------
// 3) Per-bucket degree count -> rowstart + nrm. Reads the bucket's packed
//    ebuf slice (cache-resident), LDS-histograms 128 nodes, scans locally.
// ---------------------------------------------------------------------------
__global__ __launch_bounds__(512) void deg_kernel(const int* __restrict__ gcur,
                                                  const int* __restrict__ bstart,
                                                  const int* __restrict__ ebuf,
                                                  int* __restrict__ rowstart,
                                                  float* __restrict__ nrm) {
    __shared__ int dcnt[NPB];
    __shared__ int s[NPB];
    int b = blockIdx.x;
    int t = threadIdx.x;
    if (t < NPB) dcnt[t] = 0;
    __syncthreads();

    int ecnt = gcur[b];
    if (ecnt > BCAP) ecnt = BCAP;
    for (int j = t; j < ecnt; j += 512)
        atomicAdd(&dcnt[PK_LI(ebuf[(size_t)b * BCAP + j])], 1);
    __syncthreads();

    int v = 0;
    if (t < NPB) { v = dcnt[t]; s[t] = v; }
    __syncthreads();
    for (int off = 1; off < NPB; off <<= 1) {
        int a = (t < NPB && t >= off) ? s[t - off] : 0;
        __syncthreads();
        if (t < NPB) s[t] += a;
        __syncthreads();
    }

    int nbase = b * NPB;
    int nn = N_NODES - nbase;
    if (nn > NPB) nn = NPB;
    if (t < nn) {
        rowstart[nbase + t] = bstart[b] + s[t] - v;   // exclusive
        nrm[nbase + t] = rsqrtf(fmaxf((float)v, 1.0f));
    }
    if (b == NBKT - 1 && t == 0) rowstart[N_NODES] = N_EDGES;
}

// ---------------------------------------------------------------------------
// 4) MFMA GEMM: h = relu(x @ w1^T + b1), bf16, fused gate dots.
//    Block = 256 thr (4 waves), tile M=256 N=128, BK=32, 16x16x32 MFMA.
//    4 M-frags/wave: 12 ds_read_b128 per 32 MFMA -> MFMA-bound (was 9 per 16).
// ---------------------------------------------------------------------------
__global__ __launch_bounds__(256) void gemm_kernel(const float* __restrict__ x,
                                                   const unsigned short* __restrict__ w1b,
                                                   const float* __restrict__ b1,
                                                   const float* __restrict__ gw,
                                                   const float* __restrict__ nrm,
                                                   unsigned short* __restrict__ h,
                                                   float2* __restrict__ pd_pack,
                                                   float2* __restrict__ ps_pack) {
    __shared__ unsigned short As[256 * 40];  // [m][k] bf16, stride 40 (20.5 KB)
    __shared__ unsigned short Bs[128 * 40];  // [n][k] bf16, stride 40 (10.2 KB)

    int tid = threadIdx.x;
    int bm = blockIdx.x * 256;

    int wv   = tid >> 6;
    int lane = tid & 63;
    int col  = lane & 15;
    int kq   = lane >> 4;

    f32x4 acc[4][8];
#pragma unroll
    for (int f = 0; f < 4; f++)
#pragma unroll
        for (int nf = 0; nf < 8; nf++) acc[f][nf] = (f32x4){0.f, 0.f, 0.f, 0.f};

    int am = tid >> 2;            // 0..63 (+ sub*64)
    int ak = (tid & 3) * 8;       // 0,8,16,24
    int bn = tid >> 1;            // 0..127
    int bk = (tid & 1) * 16;      // 0,16

    for (int k0 = 0; k0 < IN_DIM; k0 += 32) {
        // stage A: 256x32 f32 -> bf16 (4 sub-rows x 8 floats per thread)
        ushort8 av[4];
#pragma unroll
        for (int sub = 0; sub < 4; sub++) {
            int r = am + sub * 64;
            float4 a0 = {0,0,0,0}, a1 = {0,0,0,0};
            if (bm + r < N_NODES) {
                const float* p = &x[(size_t)(bm + r) * IN_DIM + k0 + ak];
                a0 = *(const float4*)p;
                a1 = *(const float4*)(p + 4);
            }
            av[sub][0]=f2bf(a0.x); av[sub][1]=f2bf(a0.y);
            av[sub][2]=f2bf(a0.z); av[sub][3]=f2bf(a0.w);
            av[sub][4]=f2bf(a1.x); av[sub][5]=f2bf(a1.y);
            av[sub][6]=f2bf(a1.z); av[sub][7]=f2bf(a1.w);
        }
        // stage B: already bf16 (16 elems = 2 x ushort8 per thread)
        ushort8 bv0 = *(const ushort8*)&w1b[bn * IN_DIM + k0 + bk];
        ushort8 bv1 = *(const ushort8*)&w1b[bn * IN_DIM + k0 + bk + 8];

        __syncthreads();
#pragma unroll
        for (int sub = 0; sub < 4; sub++)
            *(ushort8*)&As[(am + sub * 64) * 40 + ak] = av[sub];
        *(ushort8*)&Bs[bn * 40 + bk] = bv0;
        *(ushort8*)&Bs[bn * 40 + bk + 8] = bv1;
        __syncthreads();

        bf16x8 afrag[4];
#pragma unroll
        for (int f = 0; f < 4; f++)
            afrag[f] = *(bf16x8*)&As[(wv * 64 + f * 16 + col) * 40 + kq * 8];
#pragma unroll
        for (int nf = 0; nf < 8; nf++) {
            bf16x8 bfrag = *(bf16x8*)&Bs[(nf * 16 + col) * 40 + kq * 8];
#pragma unroll
            for (int f = 0; f < 4; f++)
                acc[f][nf] = __builtin_amdgcn_mfma_f32_16x16x32_bf16(afrag[f], bfrag,
                                                                     acc[f][nf], 0, 0, 0);
        }
    }

    float bias[8], wd[8], wsv[8];
#pragma unroll
    for (int nf = 0; nf < 8; nf++) {
        bias[nf] = b1[nf * 16 + col];
        wd[nf]   = gw[nf * 16 + col];
        wsv[nf]  = gw[HID + nf * 16 + col];
    }
#pragma unroll
    for (int f = 0; f < 4; f++) {
#pragma unroll
        for (int r = 0; r < 4; r++) {
            int gm = bm + wv * 64 + f * 16 + kq * 4 + r;  // uniform across 16 col-lanes
            float pd = 0.f, ps = 0.f;
            bool ok = (gm < N_NODES);
#pragma unroll
            for (int nf = 0; nf < 8; nf++) {
                float v = fmaxf(acc[f][nf][r] + bias[nf], 0.f);
                pd = fmaf(v, wd[nf], pd);
                ps = fmaf(v, wsv[nf], ps);
                if (ok) h[(size_t)gm * HID + nf * 16 + col] = f2bf(v);
            }
#pragma unroll
            for (int m = 1; m < 16; m <<= 1) {
                pd += __shfl_xor(pd, m);
                ps += __shfl_xor(ps, m);
            }
            if (ok && col == 0) {
                float nv = nrm[gm];
                pd_pack[gm] = make_float2(pd, nv);
                ps_pack[gm] = make_float2(ps, nv);
            }
        }
    }
}

// ---------------------------------------------------------------------------
// 5) Bucket-local CSR scatter: one block per bucket. Slot claims via LDS
//    cursors seeded from rowstart; epack writes land in this bucket's
//    contiguous ~16KB CSR range -> single-L2 full-line writebacks.
// ---------------------------------------------------------------------------
__global__ __launch_bounds__(512) void scatter2_kernel(const int* __restrict__ gcur,
                                                       const int* __restrict__ ebuf,
                                                       const int* __restrict__ rowstart,
                                                       const float2* __restrict__ pd_pack,
                                                       const float2* __restrict__ ps_pack,
                                                       const float* __restrict__ gb,
                                                       int2* __restrict__ epack) {
    __shared__ int    curs[NPB];
    __shared__ float2 pdl[NPB];
    int b = blockIdx.x;
    int t = threadIdx.x;
    int nbase = b * NPB;
    int nn = N_NODES - nbase;
    if (nn > NPB) nn = NPB;
    if (t < nn) {
        curs[t] = rowstart[nbase + t];
        pdl[t]  = pd_pack[nbase + t];
    }
    __syncthreads();

    int ecnt = gcur[b];
    if (ecnt > BCAP) ecnt = BCAP;
    float gbv = gb[0];
    for (int j = t; j < ecnt; j += 512) {
        int p = ebuf[(size_t)b * BCAP + j];
        int s  = PK_SRC(p);
        int li = PK_LI(p);
        int pos = atomicAdd(&curs[li], 1);
        float2 pdp = pdl[li];               // {a_dst[d], nrm[d]}
        float2 psp = ps_pack[s];            // {a_src[s], nrm[s]}
        float g = fast_tanh(pdp.x + psp.x + gbv);
        epack[pos] = make_int2(s, __float_as_int(g * pdp.y * psp.y));
    }
}

// ---------------------------------------------------------------------------
// 6) Aggregate: one wave per dst node; 4 edges in parallel per wave
//    (16 lanes x 8 channels each), unroll 2 -> 8 h-rows in flight.
// ---------------------------------------------------------------------------
__global__ __launch_bounds__(256) void aggregate_kernel(const int* __restrict__ rowstart,
                                                        const int2* __restrict__ epack,
                                                        const unsigned short* __restrict__ h,
                                                        float* __restrict__ out) {
    int node = blockIdx.x * 4 + (threadIdx.x >> 6);
    if (node >= N_NODES) return;
    int lane = threadIdx.x & 63;
    int q  = lane >> 4;    // 0..3: edge slot within wave
    int ql = lane & 15;    // channel group: ch = ql*8

    int beg = rowstart[node];
    int end = rowstart[node + 1];

    float acc[8];
#pragma unroll
    for (int t = 0; t < 8; t++) acc[t] = 0.f;

    int j = beg;
    for (; j + 8 <= end; j += 8) {
        int2 e0 = epack[j + q];
        int2 e1 = epack[j + 4 + q];
        ushort8 r0 = *(const ushort8*)&h[(size_t)e0.x * HID + ql * 8];
        ushort8 r1 = *(const ushort8*)&h[(size_t)e1.x * HID + ql * 8];
        float c0 = __int_as_float(e0.y);
        float c1 = __int_as_float(e1.y);
#pragma unroll
        for (int t = 0; t < 8; t++) {
            acc[t] = fmaf(c0, bf2f(r0[t]), acc[t]);
            acc[t] = fmaf(c1, bf2f(r1[t]), acc[t]);
        }
    }
    for (; j < end; j += 4) {
        bool act = (j + q) < end;
        int idx = act ? (j + q) : beg;          // beg valid: j<end => beg<end
        int2 e = epack[idx];
        ushort8 r = *(const ushort8*)&h[(size_t)e.x * HID + ql * 8];
        float c = act ? __int_as_float(e.y) : 0.f;
#pragma unroll
        for (int t = 0; t < 8; t++) acc[t] = fmaf(c, bf2f(r[t]), acc[t]);
    }
    // combine the 4 edge-slots (lane bits 4,5)
#pragma unroll
    for (int t = 0; t < 8; t++) {
        acc[t] += __shfl_xor(acc[t], 16);
        acc[t] += __shfl_xor(acc[t], 32);
    }
    if (q == 0) {
        ushort8 hd = *(const ushort8*)&h[(size_t)node * HID + ql * 8];
        f32x4 o0, o1;
        o0.x = fmaf(EPS_C, bf2f(hd[0]), acc[0]);
        o0.y = fmaf(EPS_C, bf2f(hd[1]), acc[1]);
        o0.z = fmaf(EPS_C, bf2f(hd[2]), acc[2]);
        o0.w = fmaf(EPS_C, bf2f(hd[3]), acc[3]);
        o1.x = fmaf(EPS_C, bf2f(hd[4]), acc[4]);
        o1.y = fmaf(EPS_C, bf2f(hd[5]), acc[5]);
        o1.z = fmaf(EPS_C, bf2f(hd[6]), acc[6]);
        o1.w = fmaf(EPS_C, bf2f(hd[7]), acc[7]);
        // nontemporal: out is never re-read; keep h resident in L2 instead
        __builtin_nontemporal_store(o0, (f32x4*)&out[(size_t)node * HID + ql * 8]);
        __builtin_nontemporal_store(o1, (f32x4*)&out[(size_t)node * HID + ql * 8 + 4]);
    }
}

// ---------------------------------------------------------------------------
extern "C" void kernel_launch(void* const* d_in, const int* in_sizes, int n_in,
                              void* d_out, int out_size, void* d_ws, size_t ws_size,
                              hipStream_t stream) {
    const float* x  = (const float*)d_in[0];
    const int*   ei = (const int*)d_in[1];
    const float* w1 = (const float*)d_in[2];
    const float* b1 = (const float*)d_in[3];
    const float* gw = (const float*)d_in[4];
    const float* gb = (const float*)d_in[5];
    float* out = (float*)d_out;

    const int* src = ei;
    const int* dst = ei + N_EDGES;

    uintptr_t base = (uintptr_t)d_ws;
    size_t off = 0;
    auto alloc = [&](size_t bytes) -> void* {
        void* p = (void*)(base + off);
        off += (bytes + 255) & ~(size_t)255;
        return p;
    };
    unsigned short* h   = (unsigned short*)alloc((size_t)N_NODES * HID * 2);  // 25.6 MB
    float2* pd_pack     = (float2*)alloc((size_t)N_NODES * 8);
    float2* ps_pack     = (float2*)alloc((size_t)N_NODES * 8);
    float*  nrm         = (float*)alloc((size_t)N_NODES * 4);
    int*    rowstart    = (int*)alloc((size_t)(N_NODES + 1) * 4);
    int2*   epack       = (int2*)alloc((size_t)N_EDGES * 8);
    unsigned short* w1b = (unsigned short*)alloc((size_t)HID * IN_DIM * 2);
    int*    gcur        = (int*)alloc((size_t)NBKT * 4);
    int*    bstart      = (int*)alloc((size_t)NBKT * 4);
    int*    ebuf        = (int*)alloc((size_t)NBKT * BCAP * 4);               // 9.6 MB

    (void)hipMemsetAsync(gcur, 0, (size_t)NBKT * 4, stream);

    convert_w1_kernel<<<(HID * IN_DIM / 4 + 255) / 256, 256, 0, stream>>>(w1, w1b);
    partition_kernel<<<S1_BLOCKS, 512, 0, stream>>>(src, dst, gcur, ebuf);
    bscan_kernel<<<1, 512, 0, stream>>>(gcur, bstart);
    deg_kernel<<<NBKT, 512, 0, stream>>>(gcur, bstart, ebuf, rowstart, nrm);
    gemm_kernel<<<(N_NODES + 255) / 256, 256, 0, stream>>>(x, w1b, b1, gw, nrm,
                                                           h, pd_pack, ps_pack);
    scatter2_kernel<<<NBKT, 512, 0, stream>>>(gcur, ebuf, rowstart,
                                              pd_pack, ps_pack, gb, epack);
    aggregate_kernel<<<(N_NODES + 3) / 4, 256, 0, stream>>>(rowstart, epack, h, out);
}

// Round 6
// 305.961 us; speedup vs baseline: 5.1057x; 1.0261x over previous
//
#include <hip/hip_runtime.h>
#include <math.h>
#include <stdint.h>

#define N_NODES 100000
#define N_EDGES 1600000
#define IN_DIM  256
#define HID     128
#define EPS_C   0.3f

// bucket partition for write-local CSR processing
#define NPB      128              // nodes per bucket (dst >> 7)
#define NBKT     782              // ceil(N_NODES / NPB)
#define NBKT_P   784              // padded (2 slots per claim thread, 392 used)
#define BCAP     3072             // per-bucket edge capacity (mean 2048, +22 sigma)
#define S1_CHUNK 4096             // edges per partition block
#define S1_BLOCKS 391             // ceil(N_EDGES / S1_CHUNK)
#define GC(b)    ((b) * 16)       // gcur padded: 1 counter per 64B line (kills atomic line-bounce)

// packed edge word: bits [16:0] = src (100000 < 2^17), bits [23:17] = dst & 127
#define PK_SRC(p)  ((p) & 0x1FFFF)
#define PK_LI(p)   ((p) >> 17)

typedef __attribute__((ext_vector_type(8))) __bf16 bf16x8;
typedef __attribute__((ext_vector_type(4))) float  f32x4;
typedef __attribute__((ext_vector_type(8))) unsigned short ushort8;

static __device__ __forceinline__ unsigned short f2bf(float f) {
    unsigned u = __float_as_uint(f);
    unsigned r = (u + 0x7fffu + ((u >> 16) & 1u)) >> 16;
    return (unsigned short)r;
}
static __device__ __forceinline__ float bf2f(unsigned short s) {
    return __uint_as_float((unsigned)s << 16);
}
// branch-free tanh: 1 - 2/(exp2(2x*log2e)+1); correct limits at +-inf
static __device__ __forceinline__ float fast_tanh(float x) {
    float e = __builtin_exp2f(x * 2.8853900817779268f);  // 2*log2(e)
    return 1.0f - 2.0f / (e + 1.0f);
}

// ---------------------------------------------------------------------------
// w1 -> bf16 preconvert (one-time tiny kernel, 32768 elems)
// ---------------------------------------------------------------------------
__global__ __launch_bounds__(256) void convert_w1_kernel(const float* __restrict__ w1,
                                                         unsigned short* __restrict__ w1b) {
    int i = blockIdx.x * 256 + threadIdx.x;
    if (i * 4 >= HID * IN_DIM) return;
    float4 v = *(const float4*)&w1[i * 4];
    ushort4 r;
    r.x = f2bf(v.x); r.y = f2bf(v.y); r.z = f2bf(v.z); r.w = f2bf(v.w);
    *(ushort4*)&w1b[i * 4] = r;
}

// ---------------------------------------------------------------------------
// 1) Partition-lite: bucket-group edges by dst>>7. No LDS staging sort, no
//    block scan: LDS hist -> one padded-gcur claim per nonempty bucket ->
//    per-edge LDS cursor atomic -> direct global write of packed 4B word.
// ---------------------------------------------------------------------------
__global__ __launch_bounds__(512) void partition_kernel(const int* __restrict__ src,
                                                        const int* __restrict__ dst,
                                                        int* __restrict__ gcur,
                                                        int* __restrict__ ebuf) {
    __shared__ int hist[NBKT_P];
    __shared__ int cur[NBKT_P];

    int t = threadIdx.x;
    for (int i = t; i < NBKT_P; i += 512) hist[i] = 0;
    __syncthreads();

    int base4 = blockIdx.x * (S1_CHUNK / 4);     // int4 index into src/dst
    int rem4  = N_EDGES / 4 - base4;

    int4 sv[2], dv[2];
#pragma unroll
    for (int j = 0; j < 2; j++) {
        int i4 = j * 512 + t;
        if (i4 < rem4) {
            sv[j] = *(const int4*)&src[(base4 + i4) * 4];
            dv[j] = *(const int4*)&dst[(base4 + i4) * 4];
        } else {
            dv[j] = make_int4(-1, -1, -1, -1);   // sentinel: invalid
        }
    }
#pragma unroll
    for (int j = 0; j < 2; j++) {
        if (dv[j].x >= 0) {
            atomicAdd(&hist[dv[j].x >> 7], 1);
            atomicAdd(&hist[dv[j].y >> 7], 1);
            atomicAdd(&hist[dv[j].z >> 7], 1);
            atomicAdd(&hist[dv[j].w >> 7], 1);
        }
    }
    __syncthreads();

    // one global claim per nonempty bucket (padded gcur -> no line contention)
    if (t < NBKT_P / 2) {
        int h0 = hist[2 * t], h1 = hist[2 * t + 1];
        if (h0 > 0) cur[2 * t]     = atomicAdd(&gcur[GC(2 * t)], h0);
        if (h1 > 0) cur[2 * t + 1] = atomicAdd(&gcur[GC(2 * t + 1)], h1);
    }
    __syncthreads();

#pragma unroll
    for (int j = 0; j < 2; j++) {
        if (dv[j].x >= 0) {
            int b, p;
            b = dv[j].x >> 7; p = atomicAdd(&cur[b], 1);
            if (p < BCAP) ebuf[(size_t)b * BCAP + p] = ((dv[j].x & (NPB - 1)) << 17) | sv[j].x;
            b = dv[j].y >> 7; p = atomicAdd(&cur[b], 1);
            if (p < BCAP) ebuf[(size_t)b * BCAP + p] = ((dv[j].y & (NPB - 1)) << 17) | sv[j].y;
            b = dv[j].z >> 7; p = atomicAdd(&cur[b], 1);
            if (p < BCAP) ebuf[(size_t)b * BCAP + p] = ((dv[j].z & (NPB - 1)) << 17) | sv[j].z;
            b = dv[j].w >> 7; p = atomicAdd(&cur[b], 1);
            if (p < BCAP) ebuf[(size_t)b * BCAP + p] = ((dv[j].w & (NPB - 1)) << 17) | sv[j].w;
        }
    }
}

// ---------------------------------------------------------------------------
// 2) Per-bucket degree count -> rs2[node] = {beg, end} (absolute, base
//    b*BCAP -- no global scan needed) + nrm. Replaces bscan + rowstart.
// ---------------------------------------------------------------------------
__global__ __launch_bounds__(512) void deg_kernel(const int* __restrict__ gcur,
                                                  const int* __restrict__ ebuf,
                                                  int2* __restrict__ rs2,
                                                  float* __restrict__ nrm) {
    __shared__ int dcnt[NPB];
    __shared__ int s[NPB];
    int b = blockIdx.x;
    int t = threadIdx.x;
    if (t < NPB) dcnt[t] = 0;
    __syncthreads();

    int ecnt = gcur[GC(b)];
    if (ecnt > BCAP) ecnt = BCAP;
    for (int j = t; j < ecnt; j += 512)
        atomicAdd(&dcnt[PK_LI(ebuf[(size_t)b * BCAP + j])], 1);
    __syncthreads();

    int v = 0;
    if (t < NPB) { v = dcnt[t]; s[t] = v; }
    __syncthreads();
    for (int off = 1; off < NPB; off <<= 1) {
        int a = (t < NPB && t >= off) ? s[t - off] : 0;
        __syncthreads();
        if (t < NPB) s[t] += a;
        __syncthreads();
    }

    int nbase = b * NPB;
    int nn = N_NODES - nbase;
    if (nn > NPB) nn = NPB;
    if (t < nn) {
        int incl = s[t];
        rs2[nbase + t] = make_int2(b * BCAP + incl - v, b * BCAP + incl);  // {beg,end}
        nrm[nbase + t] = rsqrtf(fmaxf((float)v, 1.0f));
    }
}

// ---------------------------------------------------------------------------
// 3) MFMA GEMM: h = relu(x @ w1^T + b1), bf16, fused gate dots.
//    Barrier-free k-loop: full w1b (64 KB) staged once in LDS with XOR-
//    swizzled 16B chunks (conflict-free ds_read_b128); A-fragments stream
//    directly from global x (each element read exactly once, 16 rows x 128B
//    per wave, coalesced) with 1-step register prefetch.
//    Block = 512 thr (8 waves), M=128 rows/block, grid 782, 2 blocks/CU.
// ---------------------------------------------------------------------------
__global__ __launch_bounds__(512) void gemm_kernel(const float* __restrict__ x,
                                                   const unsigned short* __restrict__ w1b,
                                                   const float* __restrict__ b1,
                                                   const float* __restrict__ gw,
                                                   const float* __restrict__ nrm,
                                                   unsigned short* __restrict__ h,
                                                   float2* __restrict__ pd_pack,
                                                   float2* __restrict__ ps_pack) {
    __shared__ unsigned short Bs[HID * IN_DIM];   // 64 KB, swizzled 16B chunks

    int tid  = threadIdx.x;
    int bm   = blockIdx.x * 128;
    int wv   = tid >> 6;          // 0..7
    int lane = tid & 63;
    int col  = lane & 15;
    int kq   = lane >> 4;         // 0..3

    // stage B once: thread t stages row n = t>>2, chunks k8 = (t&3)*8 + j.
    // chunk (n,k8) -> byte n*512 + ((k8 ^ (n&7))*16): read-side conflict-free.
    {
        int n   = tid >> 2;
        int k8b = (tid & 3) * 8;
        const ushort8* srcp = (const ushort8*)&w1b[n * IN_DIM + k8b * 8];
#pragma unroll
        for (int j = 0; j < 8; j++) {
            int k8 = k8b + j;
            *(ushort8*)((char*)Bs + n * 512 + ((k8 ^ (n & 7)) * 16)) = srcp[j];
        }
    }

    f32x4 acc[8];
#pragma unroll
    for (int nf = 0; nf < 8; nf++) acc[nf] = (f32x4){0.f, 0.f, 0.f, 0.f};

    int row  = bm + wv * 16 + col;
    bool rok = row < N_NODES;
    const float* ap = &x[(size_t)row * IN_DIM + kq * 8];

    float4 a0 = {0, 0, 0, 0}, a1 = {0, 0, 0, 0};
    if (rok) { a0 = *(const float4*)ap; a1 = *(const float4*)(ap + 4); }

    __syncthreads();   // Bs ready; no barriers after this point

    for (int k0 = 0; k0 < IN_DIM; k0 += 32) {
        // prefetch next A slice
        float4 n0 = {0, 0, 0, 0}, n1 = {0, 0, 0, 0};
        if (k0 + 32 < IN_DIM && rok) {
            n0 = *(const float4*)(ap + k0 + 32);
            n1 = *(const float4*)(ap + k0 + 36);
        }
        ushort8 av;
        av[0] = f2bf(a0.x); av[1] = f2bf(a0.y); av[2] = f2bf(a0.z); av[3] = f2bf(a0.w);
        av[4] = f2bf(a1.x); av[5] = f2bf(a1.y); av[6] = f2bf(a1.z); av[7] = f2bf(a1.w);
        bf16x8 afrag = *(bf16x8*)&av;

        int swz = ((k0 >> 3) + kq) ^ (col & 7);   // n&7 == col&7 (nf*16 = 0 mod 8)
#pragma unroll
        for (int nf = 0; nf < 8; nf++) {
            int n = nf * 16 + col;
            bf16x8 bfrag = *(bf16x8*)((char*)Bs + n * 512 + swz * 16);
            acc[nf] = __builtin_amdgcn_mfma_f32_16x16x32_bf16(afrag, bfrag, acc[nf], 0, 0, 0);
        }
        a0 = n0; a1 = n1;
    }

    float bias[8], wd[8], wsv[8];
#pragma unroll
    for (int nf = 0; nf < 8; nf++) {
        bias[nf] = b1[nf * 16 + col];
        wd[nf]   = gw[nf * 16 + col];
        wsv[nf]  = gw[HID + nf * 16 + col];
    }
#pragma unroll
    for (int r = 0; r < 4; r++) {
        int gm = bm + wv * 16 + kq * 4 + r;   // uniform across the 16 col-lanes
        float pd = 0.f, ps = 0.f;
        bool ok = (gm < N_NODES);
#pragma unroll
        for (int nf = 0; nf < 8; nf++) {
            float v = fmaxf(acc[nf][r] + bias[nf], 0.f);
            pd = fmaf(v, wd[nf], pd);
            ps = fmaf(v, wsv[nf], ps);
            if (ok) h[(size_t)gm * HID + nf * 16 + col] = f2bf(v);
        }
#pragma unroll
        for (int m = 1; m < 16; m <<= 1) {
            pd += __shfl_xor(pd, m);
            ps += __shfl_xor(ps, m);
        }
        if (ok && col == 0) {
            float nv = nrm[gm];
            pd_pack[gm] = make_float2(pd, nv);
            ps_pack[gm] = make_float2(ps, nv);
        }
    }
}

// ---------------------------------------------------------------------------
// 4) Bucket-local CSR scatter: one block per bucket. Slot claims via LDS
//    cursors seeded from rs2; epack writes land in this bucket's contiguous
//    region [b*BCAP ...) -> single-L2 full-line writebacks.
// ---------------------------------------------------------------------------
__global__ __launch_bounds__(512) void scatter2_kernel(const int* __restrict__ gcur,
                                                       const int* __restrict__ ebuf,
                                                       const int2* __restrict__ rs2,
                                                       const float2* __restrict__ pd_pack,
                                                       const float2* __restrict__ ps_pack,
                                                       const float* __restrict__ gb,
                                                       int2* __restrict__ epack) {
    __shared__ int    curs[NPB];
    __shared__ float2 pdl[NPB];
    int b = blockIdx.x;
    int t = threadIdx.x;
    int nbase = b * NPB;
    int nn = N_NODES - nbase;
    if (nn > NPB) nn = NPB;
    if (t < nn) {
        curs[t] = rs2[nbase + t].x;
        pdl[t]  = pd_pack[nbase + t];
    }
    __syncthreads();

    int ecnt = gcur[GC(b)];
    if (ecnt > BCAP) ecnt = BCAP;
    float gbv = gb[0];
    for (int j = t; j < ecnt; j += 512) {
        int p = ebuf[(size_t)b * BCAP + j];
        int s  = PK_SRC(p);
        int li = PK_LI(p);
        int pos = atomicAdd(&curs[li], 1);
        float2 pdp = pdl[li];               // {a_dst[d], nrm[d]}
        float2 psp = ps_pack[s];            // {a_src[s], nrm[s]}
        float g = fast_tanh(pdp.x + psp.x + gbv);
        epack[pos] = make_int2(s, __float_as_int(g * pdp.y * psp.y));
    }
}

// ---------------------------------------------------------------------------
// 5) Aggregate: one wave per dst node; 4 edges in parallel per wave
//    (16 lanes x 8 channels each), unroll 2 -> 8 h-rows in flight.
// ---------------------------------------------------------------------------
__global__ __launch_bounds__(256) void aggregate_kernel(const int2* __restrict__ rs2,
                                                        const int2* __restrict__ epack,
                                                        const unsigned short* __restrict__ h,
                                                        float* __restrict__ out) {
    int node = blockIdx.x * 4 + (threadIdx.x >> 6);
    if (node >= N_NODES) return;
    int lane = threadIdx.x & 63;
    int q  = lane >> 4;    // 0..3: edge slot within wave
    int ql = lane & 15;    // channel group: ch = ql*8

    int2 be = rs2[node];
    int beg = be.x;
    int end = be.y;

    float acc[8];
#pragma unroll
    for (int t = 0; t < 8; t++) acc[t] = 0.f;

    int j = beg;
    for (; j + 8 <= end; j += 8) {
        int2 e0 = epack[j + q];
        int2 e1 = epack[j + 4 + q];
        ushort8 r0 = *(const ushort8*)&h[(size_t)e0.x * HID + ql * 8];
        ushort8 r1 = *(const ushort8*)&h[(size_t)e1.x * HID + ql * 8];
        float c0 = __int_as_float(e0.y);
        float c1 = __int_as_float(e1.y);
#pragma unroll
        for (int t = 0; t < 8; t++) {
            acc[t] = fmaf(c0, bf2f(r0[t]), acc[t]);
            acc[t] = fmaf(c1, bf2f(r1[t]), acc[t]);
        }
    }
    for (; j < end; j += 4) {
        bool act = (j + q) < end;
        int idx = act ? (j + q) : beg;          // beg valid: j<end => beg<end
        int2 e = epack[idx];
        ushort8 r = *(const ushort8*)&h[(size_t)e.x * HID + ql * 8];
        float c = act ? __int_as_float(e.y) : 0.f;
#pragma unroll
        for (int t = 0; t < 8; t++) acc[t] = fmaf(c, bf2f(r[t]), acc[t]);
    }
    // combine the 4 edge-slots (lane bits 4,5)
#pragma unroll
    for (int t = 0; t < 8; t++) {
        acc[t] += __shfl_xor(acc[t], 16);
        acc[t] += __shfl_xor(acc[t], 32);
    }
    if (q == 0) {
        ushort8 hd = *(const ushort8*)&h[(size_t)node * HID + ql * 8];
        f32x4 o0, o1;
        o0.x = fmaf(EPS_C, bf2f(hd[0]), acc[0]);
        o0.y = fmaf(EPS_C, bf2f(hd[1]), acc[1]);
        o0.z = fmaf(EPS_C, bf2f(hd[2]), acc[2]);
        o0.w = fmaf(EPS_C, bf2f(hd[3]), acc[3]);
        o1.x = fmaf(EPS_C, bf2f(hd[4]), acc[4]);
        o1.y = fmaf(EPS_C, bf2f(hd[5]), acc[5]);
        o1.z = fmaf(EPS_C, bf2f(hd[6]), acc[6]);
        o1.w = fmaf(EPS_C, bf2f(hd[7]), acc[7]);
        // nontemporal: out is never re-read; keep h resident in L2 instead
        __builtin_nontemporal_store(o0, (f32x4*)&out[(size_t)node * HID + ql * 8]);
        __builtin_nontemporal_store(o1, (f32x4*)&out[(size_t)node * HID + ql * 8 + 4]);
    }
}

// ---------------------------------------------------------------------------
extern "C" void kernel_launch(void* const* d_in, const int* in_sizes, int n_in,
                              void* d_out, int out_size, void* d_ws, size_t ws_size,
                              hipStream_t stream) {
    const float* x  = (const float*)d_in[0];
    const int*   ei = (const int*)d_in[1];
    const float* w1 = (const float*)d_in[2];
    const float* b1 = (const float*)d_in[3];
    const float* gw = (const float*)d_in[4];
    const float* gb = (const float*)d_in[5];
    float* out = (float*)d_out;

    const int* src = ei;
    const int* dst = ei + N_EDGES;

    uintptr_t base = (uintptr_t)d_ws;
    size_t off = 0;
    auto alloc = [&](size_t bytes) -> void* {
        void* p = (void*)(base + off);
        off += (bytes + 255) & ~(size_t)255;
        return p;
    };
    unsigned short* h   = (unsigned short*)alloc((size_t)N_NODES * HID * 2);  // 25.6 MB
    float2* pd_pack     = (float2*)alloc((size_t)N_NODES * 8);
    float2* ps_pack     = (float2*)alloc((size_t)N_NODES * 8);
    float*  nrm         = (float*)alloc((size_t)N_NODES * 4);
    int2*   rs2         = (int2*)alloc((size_t)N_NODES * 8);
    int2*   epack       = (int2*)alloc((size_t)NBKT * BCAP * 8);              // 19.2 MB
    unsigned short* w1b = (unsigned short*)alloc((size_t)HID * IN_DIM * 2);
    int*    gcur        = (int*)alloc((size_t)NBKT * 16 * 4);                 // 64B-padded
    int*    ebuf        = (int*)alloc((size_t)NBKT * BCAP * 4);               // 9.6 MB

    (void)hipMemsetAsync(gcur, 0, (size_t)NBKT * 16 * 4, stream);

    convert_w1_kernel<<<(HID * IN_DIM / 4 + 255) / 256, 256, 0, stream>>>(w1, w1b);
    partition_kernel<<<S1_BLOCKS, 512, 0, stream>>>(src, dst, gcur, ebuf);
    deg_kernel<<<NBKT, 512, 0, stream>>>(gcur, ebuf, rs2, nrm);
    gemm_kernel<<<(N_NODES + 127) / 128, 512, 0, stream>>>(x, w1b, b1, gw, nrm,
                                                           h, pd_pack, ps_pack);
    scatter2_kernel<<<NBKT, 512, 0, stream>>>(gcur, ebuf, rs2,
                                              pd_pack, ps_pack, gb, epack);
    aggregate_kernel<<<(N_NODES + 3) / 4, 256, 0, stream>>>(rs2, epack, h, out);
}

// Round 7
// 304.660 us; speedup vs baseline: 5.1275x; 1.0043x over previous
//
#include <hip/hip_runtime.h>
#include <math.h>
#include <stdint.h>

#define N_NODES 100000
#define N_EDGES 1600000
#define IN_DIM  256
#define HID     128
#define EPS_C   0.3f

// bucket partition for write-local CSR processing
#define NPB      128              // nodes per bucket (dst >> 7)
#define NBKT     782              // ceil(N_NODES / NPB)
#define NBKT_P   784              // padded (2 slots per claim thread, 392 used)
#define BCAP     3072             // per-bucket edge capacity (mean 2048, +22 sigma)
#define S1_CHUNK 4096             // edges per partition block
#define S1_BLOCKS 391             // ceil(N_EDGES / S1_CHUNK)
#define GC(b)    ((b) * 16)       // gcur padded: 1 counter per 64B line (kills atomic line-bounce)

// packed edge word: bits [16:0] = src (100000 < 2^17), bits [23:17] = dst & 127
#define PK_SRC(p)  ((p) & 0x1FFFF)
#define PK_LI(p)   ((p) >> 17)

typedef __attribute__((ext_vector_type(8))) __bf16 bf16x8;
typedef __attribute__((ext_vector_type(4))) float  f32x4;
typedef __attribute__((ext_vector_type(8))) unsigned short ushort8;

static __device__ __forceinline__ unsigned short f2bf(float f) {
    unsigned u = __float_as_uint(f);
    unsigned r = (u + 0x7fffu + ((u >> 16) & 1u)) >> 16;
    return (unsigned short)r;
}
static __device__ __forceinline__ float bf2f(unsigned short s) {
    return __uint_as_float((unsigned)s << 16);
}
// branch-free tanh: 1 - 2/(exp2(2x*log2e)+1); correct limits at +-inf
static __device__ __forceinline__ float fast_tanh(float x) {
    float e = __builtin_exp2f(x * 2.8853900817779268f);  // 2*log2(e)
    return 1.0f - 2.0f / (e + 1.0f);
}

// ---------------------------------------------------------------------------
// w1 -> bf16 preconvert (one-time tiny kernel, 32768 elems)
// ---------------------------------------------------------------------------
__global__ __launch_bounds__(256) void convert_w1_kernel(const float* __restrict__ w1,
                                                         unsigned short* __restrict__ w1b) {
    int i = blockIdx.x * 256 + threadIdx.x;
    if (i * 4 >= HID * IN_DIM) return;
    float4 v = *(const float4*)&w1[i * 4];
    ushort4 r;
    r.x = f2bf(v.x); r.y = f2bf(v.y); r.z = f2bf(v.z); r.w = f2bf(v.w);
    *(ushort4*)&w1b[i * 4] = r;
}

// ---------------------------------------------------------------------------
// 1) Partition-lite: bucket-group edges by dst>>7. No LDS staging sort, no
//    block scan: LDS hist -> one padded-gcur claim per nonempty bucket ->
//    per-edge LDS cursor atomic -> direct global write of packed 4B word.
// ---------------------------------------------------------------------------
__global__ __launch_bounds__(512) void partition_kernel(const int* __restrict__ src,
                                                        const int* __restrict__ dst,
                                                        int* __restrict__ gcur,
                                                        int* __restrict__ ebuf) {
    __shared__ int hist[NBKT_P];
    __shared__ int cur[NBKT_P];

    int t = threadIdx.x;
    for (int i = t; i < NBKT_P; i += 512) hist[i] = 0;
    __syncthreads();

    int base4 = blockIdx.x * (S1_CHUNK / 4);     // int4 index into src/dst
    int rem4  = N_EDGES / 4 - base4;

    int4 sv[2], dv[2];
#pragma unroll
    for (int j = 0; j < 2; j++) {
        int i4 = j * 512 + t;
        if (i4 < rem4) {
            sv[j] = *(const int4*)&src[(base4 + i4) * 4];
            dv[j] = *(const int4*)&dst[(base4 + i4) * 4];
        } else {
            dv[j] = make_int4(-1, -1, -1, -1);   // sentinel: invalid
        }
    }
#pragma unroll
    for (int j = 0; j < 2; j++) {
        if (dv[j].x >= 0) {
            atomicAdd(&hist[dv[j].x >> 7], 1);
            atomicAdd(&hist[dv[j].y >> 7], 1);
            atomicAdd(&hist[dv[j].z >> 7], 1);
            atomicAdd(&hist[dv[j].w >> 7], 1);
        }
    }
    __syncthreads();

    // one global claim per nonempty bucket (padded gcur -> no line contention)
    if (t < NBKT_P / 2) {
        int h0 = hist[2 * t], h1 = hist[2 * t + 1];
        if (h0 > 0) cur[2 * t]     = atomicAdd(&gcur[GC(2 * t)], h0);
        if (h1 > 0) cur[2 * t + 1] = atomicAdd(&gcur[GC(2 * t + 1)], h1);
    }
    __syncthreads();

#pragma unroll
    for (int j = 0; j < 2; j++) {
        if (dv[j].x >= 0) {
            int b, p;
            b = dv[j].x >> 7; p = atomicAdd(&cur[b], 1);
            if (p < BCAP) ebuf[(size_t)b * BCAP + p] = ((dv[j].x & (NPB - 1)) << 17) | sv[j].x;
            b = dv[j].y >> 7; p = atomicAdd(&cur[b], 1);
            if (p < BCAP) ebuf[(size_t)b * BCAP + p] = ((dv[j].y & (NPB - 1)) << 17) | sv[j].y;
            b = dv[j].z >> 7; p = atomicAdd(&cur[b], 1);
            if (p < BCAP) ebuf[(size_t)b * BCAP + p] = ((dv[j].z & (NPB - 1)) << 17) | sv[j].z;
            b = dv[j].w >> 7; p = atomicAdd(&cur[b], 1);
            if (p < BCAP) ebuf[(size_t)b * BCAP + p] = ((dv[j].w & (NPB - 1)) << 17) | sv[j].w;
        }
    }
}

// ---------------------------------------------------------------------------
// 2) Per-bucket degree count -> rs2[node] = {beg, end} (absolute, base
//    b*BCAP -- no global scan needed) + nrm. Replaces bscan + rowstart.
// ---------------------------------------------------------------------------
__global__ __launch_bounds__(512) void deg_kernel(const int* __restrict__ gcur,
                                                  const int* __restrict__ ebuf,
                                                  int2* __restrict__ rs2,
                                                  float* __restrict__ nrm) {
    __shared__ int dcnt[NPB];
    __shared__ int s[NPB];
    int b = blockIdx.x;
    int t = threadIdx.x;
    if (t < NPB) dcnt[t] = 0;
    __syncthreads();

    int ecnt = gcur[GC(b)];
    if (ecnt > BCAP) ecnt = BCAP;
    for (int j = t; j < ecnt; j += 512)
        atomicAdd(&dcnt[PK_LI(ebuf[(size_t)b * BCAP + j])], 1);
    __syncthreads();

    int v = 0;
    if (t < NPB) { v = dcnt[t]; s[t] = v; }
    __syncthreads();
    for (int off = 1; off < NPB; off <<= 1) {
        int a = (t < NPB && t >= off) ? s[t - off] : 0;
        __syncthreads();
        if (t < NPB) s[t] += a;
        __syncthreads();
    }

    int nbase = b * NPB;
    int nn = N_NODES - nbase;
    if (nn > NPB) nn = NPB;
    if (t < nn) {
        int incl = s[t];
        rs2[nbase + t] = make_int2(b * BCAP + incl - v, b * BCAP + incl);  // {beg,end}
        nrm[nbase + t] = rsqrtf(fmaxf((float)v, 1.0f));
    }
}

// ---------------------------------------------------------------------------
// 3) MFMA GEMM: h = relu(x @ w1^T + b1), bf16, fused gate dots.
//    w1b (64 KB) staged once in LDS (XOR-swizzled, read- AND write-
//    conflict-free); k-loop fully unrolled with ALL 16 x-float4 loads
//    hoisted into one prologue batch -> 16-deep MLP per wave, streaming
//    (was 1-deep prefetch = latency-bound at 67us).
//    Block = 512 thr (8 waves), M=128 rows/block, grid 782, 2 blocks/CU.
// ---------------------------------------------------------------------------
__global__ __launch_bounds__(512, 4) void gemm_kernel(const float* __restrict__ x,
                                                      const unsigned short* __restrict__ w1b,
                                                      const float* __restrict__ b1,
                                                      const float* __restrict__ gw,
                                                      const float* __restrict__ nrm,
                                                      unsigned short* __restrict__ h,
                                                      float2* __restrict__ pd_pack,
                                                      float2* __restrict__ ps_pack) {
    __shared__ unsigned short Bs[HID * IN_DIM];   // 64 KB, swizzled 16B chunks

    int tid  = threadIdx.x;
    int bm   = blockIdx.x * 128;
    int wv   = tid >> 6;          // 0..7
    int lane = tid & 63;
    int col  = lane & 15;
    int kq   = lane >> 4;         // 0..3

    // stage B once: thread t stages row n = t>>2, chunks c = (t&3) + 4*j
    // (stride-4 order: per 8-lane phase the stored positions span a 4-set
    //  with 2 lanes each -> 2-way = free; old (t&3)*8+j order was 4-way).
    // chunk (n,c) -> byte n*512 + ((c ^ (n&7))*16): read-side conflict-free.
    {
        int n  = tid >> 2;
        int c0 = tid & 3;
        const unsigned short* srcp = &w1b[n * IN_DIM];
#pragma unroll
        for (int j = 0; j < 8; j++) {
            int c = c0 + 4 * j;
            *(ushort8*)((char*)Bs + n * 512 + ((c ^ (n & 7)) * 16)) =
                *(const ushort8*)&srcp[c * 8];
        }
    }

    f32x4 acc[8];
#pragma unroll
    for (int nf = 0; nf < 8; nf++) acc[nf] = (f32x4){0.f, 0.f, 0.f, 0.f};

    int row  = bm + wv * 16 + col;
    bool rok = row < N_NODES;
    const float* ap = &x[(size_t)row * IN_DIM + kq * 8];

    // load ALL of this lane's x slice (16 float4 = 64 floats), convert to
    // 8 bf16 fragments. Static indices (full unroll) -> registers, max MLP.
    bf16x8 af[8];
#pragma unroll
    for (int i = 0; i < 8; i++) {
        float4 a0 = {0, 0, 0, 0}, a1 = {0, 0, 0, 0};
        if (rok) {
            a0 = *(const float4*)(ap + 32 * i);
            a1 = *(const float4*)(ap + 32 * i + 4);
        }
        ushort8 av;
        av[0] = f2bf(a0.x); av[1] = f2bf(a0.y); av[2] = f2bf(a0.z); av[3] = f2bf(a0.w);
        av[4] = f2bf(a1.x); av[5] = f2bf(a1.y); av[6] = f2bf(a1.z); av[7] = f2bf(a1.w);
        af[i] = *(bf16x8*)&av;
    }

    __syncthreads();   // Bs ready; no barriers after this point

#pragma unroll
    for (int i = 0; i < 8; i++) {                 // k0 = 32*i
        int swz = (4 * i + kq) ^ (col & 7);       // chunk (k0>>3)+kq, xor row&7
#pragma unroll
        for (int nf = 0; nf < 8; nf++) {
            int n = nf * 16 + col;
            bf16x8 bfrag = *(bf16x8*)((char*)Bs + n * 512 + swz * 16);
            acc[nf] = __builtin_amdgcn_mfma_f32_16x16x32_bf16(af[i], bfrag, acc[nf], 0, 0, 0);
        }
    }

    float bias[8], wd[8], wsv[8];
#pragma unroll
    for (int nf = 0; nf < 8; nf++) {
        bias[nf] = b1[nf * 16 + col];
        wd[nf]   = gw[nf * 16 + col];
        wsv[nf]  = gw[HID + nf * 16 + col];
    }
#pragma unroll
    for (int r = 0; r < 4; r++) {
        int gm = bm + wv * 16 + kq * 4 + r;   // uniform across the 16 col-lanes
        float pd = 0.f, ps = 0.f;
        bool ok = (gm < N_NODES);
#pragma unroll
        for (int nf = 0; nf < 8; nf++) {
            float v = fmaxf(acc[nf][r] + bias[nf], 0.f);
            pd = fmaf(v, wd[nf], pd);
            ps = fmaf(v, wsv[nf], ps);
            if (ok) h[(size_t)gm * HID + nf * 16 + col] = f2bf(v);
        }
#pragma unroll
        for (int m = 1; m < 16; m <<= 1) {
            pd += __shfl_xor(pd, m);
            ps += __shfl_xor(ps, m);
        }
        if (ok && col == 0) {
            float nv = nrm[gm];
            pd_pack[gm] = make_float2(pd, nv);
            ps_pack[gm] = make_float2(ps, nv);
        }
    }
}

// ---------------------------------------------------------------------------
// 4) Bucket-local CSR scatter: one block per bucket. Slot claims via LDS
//    cursors seeded from rs2; epack writes land in this bucket's contiguous
//    region [b*BCAP ...) -> single-L2 full-line writebacks.
// ---------------------------------------------------------------------------
__global__ __launch_bounds__(512) void scatter2_kernel(const int* __restrict__ gcur,
                                                       const int* __restrict__ ebuf,
                                                       const int2* __restrict__ rs2,
                                                       const float2* __restrict__ pd_pack,
                                                       const float2* __restrict__ ps_pack,
                                                       const float* __restrict__ gb,
                                                       int2* __restrict__ epack) {
    __shared__ int    curs[NPB];
    __shared__ float2 pdl[NPB];
    int b = blockIdx.x;
    int t = threadIdx.x;
    int nbase = b * NPB;
    int nn = N_NODES - nbase;
    if (nn > NPB) nn = NPB;
    if (t < nn) {
        curs[t] = rs2[nbase + t].x;
        pdl[t]  = pd_pack[nbase + t];
    }
    __syncthreads();

    int ecnt = gcur[GC(b)];
    if (ecnt > BCAP) ecnt = BCAP;
    float gbv = gb[0];
    for (int j = t; j < ecnt; j += 512) {
        int p = ebuf[(size_t)b * BCAP + j];
        int s  = PK_SRC(p);
        int li = PK_LI(p);
        int pos = atomicAdd(&curs[li], 1);
        float2 pdp = pdl[li];               // {a_dst[d], nrm[d]}
        float2 psp = ps_pack[s];            // {a_src[s], nrm[s]}
        float g = fast_tanh(pdp.x + psp.x + gbv);
        epack[pos] = make_int2(s, __float_as_int(g * pdp.y * psp.y));
    }
}

// ---------------------------------------------------------------------------
// 5) Aggregate: one wave per dst node; 4 edges in parallel per wave
//    (16 lanes x 8 channels each), unroll 2 -> 8 h-rows in flight.
// ---------------------------------------------------------------------------
__global__ __launch_bounds__(256) void aggregate_kernel(const int2* __restrict__ rs2,
                                                        const int2* __restrict__ epack,
                                                        const unsigned short* __restrict__ h,
                                                        float* __restrict__ out) {
    int node = blockIdx.x * 4 + (threadIdx.x >> 6);
    if (node >= N_NODES) return;
    int lane = threadIdx.x & 63;
    int q  = lane >> 4;    // 0..3: edge slot within wave
    int ql = lane & 15;    // channel group: ch = ql*8

    int2 be = rs2[node];
    int beg = be.x;
    int end = be.y;

    float acc[8];
#pragma unroll
    for (int t = 0; t < 8; t++) acc[t] = 0.f;

    int j = beg;
    for (; j + 8 <= end; j += 8) {
        int2 e0 = epack[j + q];
        int2 e1 = epack[j + 4 + q];
        ushort8 r0 = *(const ushort8*)&h[(size_t)e0.x * HID + ql * 8];
        ushort8 r1 = *(const ushort8*)&h[(size_t)e1.x * HID + ql * 8];
        float c0 = __int_as_float(e0.y);
        float c1 = __int_as_float(e1.y);
#pragma unroll
        for (int t = 0; t < 8; t++) {
            acc[t] = fmaf(c0, bf2f(r0[t]), acc[t]);
            acc[t] = fmaf(c1, bf2f(r1[t]), acc[t]);
        }
    }
    for (; j < end; j += 4) {
        bool act = (j + q) < end;
        int idx = act ? (j + q) : beg;          // beg valid: j<end => beg<end
        int2 e = epack[idx];
        ushort8 r = *(const ushort8*)&h[(size_t)e.x * HID + ql * 8];
        float c = act ? __int_as_float(e.y) : 0.f;
#pragma unroll
        for (int t = 0; t < 8; t++) acc[t] = fmaf(c, bf2f(r[t]), acc[t]);
    }
    // combine the 4 edge-slots (lane bits 4,5)
#pragma unroll
    for (int t = 0; t < 8; t++) {
        acc[t] += __shfl_xor(acc[t], 16);
        acc[t] += __shfl_xor(acc[t], 32);
    }
    if (q == 0) {
        ushort8 hd = *(const ushort8*)&h[(size_t)node * HID + ql * 8];
        f32x4 o0, o1;
        o0.x = fmaf(EPS_C, bf2f(hd[0]), acc[0]);
        o0.y = fmaf(EPS_C, bf2f(hd[1]), acc[1]);
        o0.z = fmaf(EPS_C, bf2f(hd[2]), acc[2]);
        o0.w = fmaf(EPS_C, bf2f(hd[3]), acc[3]);
        o1.x = fmaf(EPS_C, bf2f(hd[4]), acc[4]);
        o1.y = fmaf(EPS_C, bf2f(hd[5]), acc[5]);
        o1.z = fmaf(EPS_C, bf2f(hd[6]), acc[6]);
        o1.w = fmaf(EPS_C, bf2f(hd[7]), acc[7]);
        // nontemporal: out is never re-read; keep h resident in L2 instead
        __builtin_nontemporal_store(o0, (f32x4*)&out[(size_t)node * HID + ql * 8]);
        __builtin_nontemporal_store(o1, (f32x4*)&out[(size_t)node * HID + ql * 8 + 4]);
    }
}

// ---------------------------------------------------------------------------
extern "C" void kernel_launch(void* const* d_in, const int* in_sizes, int n_in,
                              void* d_out, int out_size, void* d_ws, size_t ws_size,
                              hipStream_t stream) {
    const float* x  = (const float*)d_in[0];
    const int*   ei = (const int*)d_in[1];
    const float* w1 = (const float*)d_in[2];
    const float* b1 = (const float*)d_in[3];
    const float* gw = (const float*)d_in[4];
    const float* gb = (const float*)d_in[5];
    float* out = (float*)d_out;

    const int* src = ei;
    const int* dst = ei + N_EDGES;

    uintptr_t base = (uintptr_t)d_ws;
    size_t off = 0;
    auto alloc = [&](size_t bytes) -> void* {
        void* p = (void*)(base + off);
        off += (bytes + 255) & ~(size_t)255;
        return p;
    };
    unsigned short* h   = (unsigned short*)alloc((size_t)N_NODES * HID * 2);  // 25.6 MB
    float2* pd_pack     = (float2*)alloc((size_t)N_NODES * 8);
    float2* ps_pack     = (float2*)alloc((size_t)N_NODES * 8);
    float*  nrm         = (float*)alloc((size_t)N_NODES * 4);
    int2*   rs2         = (int2*)alloc((size_t)N_NODES * 8);
    int2*   epack       = (int2*)alloc((size_t)NBKT * BCAP * 8);              // 19.2 MB
    unsigned short* w1b = (unsigned short*)alloc((size_t)HID * IN_DIM * 2);
    int*    gcur        = (int*)alloc((size_t)NBKT * 16 * 4);                 // 64B-padded
    int*    ebuf        = (int*)alloc((size_t)NBKT * BCAP * 4);               // 9.6 MB

    (void)hipMemsetAsync(gcur, 0, (size_t)NBKT * 16 * 4, stream);

    convert_w1_kernel<<<(HID * IN_DIM / 4 + 255) / 256, 256, 0, stream>>>(w1, w1b);
    partition_kernel<<<S1_BLOCKS, 512, 0, stream>>>(src, dst, gcur, ebuf);
    deg_kernel<<<NBKT, 512, 0, stream>>>(gcur, ebuf, rs2, nrm);
    gemm_kernel<<<(N_NODES + 127) / 128, 512, 0, stream>>>(x, w1b, b1, gw, nrm,
                                                           h, pd_pack, ps_pack);
    scatter2_kernel<<<NBKT, 512, 0, stream>>>(gcur, ebuf, rs2,
                                              pd_pack, ps_pack, gb, epack);
    aggregate_kernel<<<(N_NODES + 3) / 4, 256, 0, stream>>>(rs2, epack, h, out);
}